// Round 5
// baseline (160.400 us; speedup 1.0000x reference)
//
#include <hip/hip_runtime.h>
#include <stdint.h>

#define HB 18                   // low bits within a coarse bucket
#define HIST1_SIZE 8192         // top 13 bits of (bits & 0x7fffffff)
#define CAND_CAP 8192
#define LIST_CAP 1500000
#define LBUF_CAP 3072
#define PAIR_CAP 1024
#define PEAK_CAP 512
#define MAX_SPIKE 36
#define STAGE_BLOCKS 128

// params indices
#define P_B1    0
#define P_B2    1
#define P_R1    2
#define P_R2    3
#define P_THRLO 4
#define P_THR   5
#define P_CANDN 6
#define P_LISTN 7
#define P_BINA0 8
#define P_BINA1 9
#define P_RA0   10
#define P_RA1   11
#define P_DONEA 12
#define P_DONEB 13

// ws byte layout (zeroed region first)
#define WS_HIST1   0              // 8192*4 = 32768
#define WS_HISTA   32768          // 512*4  = 2048  -> 34816
#define WS_HISTB   34816          // 2048*4 = 8192  -> 43008
#define WS_PARAMS  43008          // 64            -> 43072
#define WS_ZERO_BYTES 43072
#define WS_CAND    43072          // 8192*4 -> 75840
#define WS_LIST    76800          // 1.5M*4 = 6MB

// ---------------- pass 1: 13-bit histogram, 8x load batching ----------------
__global__ __launch_bounds__(256) void k_hist1(const float* __restrict__ x, int N,
                                               int* __restrict__ hist1) {
  __shared__ int h[HIST1_SIZE];
  for (int i = threadIdx.x; i < HIST1_SIZE; i += 256) h[i] = 0;
  __syncthreads();
  int NV = N >> 2;
  int str = gridDim.x * 256;
  const float4* vec = reinterpret_cast<const float4*>(x);
  int j = blockIdx.x * 256 + threadIdx.x;
  for (; j + 7 * str < NV; j += 8 * str) {
    float4 v[8];
#pragma unroll
    for (int k = 0; k < 8; ++k) v[k] = vec[j + k * str];
#pragma unroll
    for (int k = 0; k < 8; ++k) {
      atomicAdd(&h[(__float_as_uint(v[k].x) & 0x7fffffffu) >> HB], 1);
      atomicAdd(&h[(__float_as_uint(v[k].y) & 0x7fffffffu) >> HB], 1);
      atomicAdd(&h[(__float_as_uint(v[k].z) & 0x7fffffffu) >> HB], 1);
      atomicAdd(&h[(__float_as_uint(v[k].w) & 0x7fffffffu) >> HB], 1);
    }
  }
  for (; j < NV; j += str) {
    float4 a = vec[j];
    atomicAdd(&h[(__float_as_uint(a.x) & 0x7fffffffu) >> HB], 1);
    atomicAdd(&h[(__float_as_uint(a.y) & 0x7fffffffu) >> HB], 1);
    atomicAdd(&h[(__float_as_uint(a.z) & 0x7fffffffu) >> HB], 1);
    atomicAdd(&h[(__float_as_uint(a.w) & 0x7fffffffu) >> HB], 1);
  }
  if (blockIdx.x == 0 && threadIdx.x == 0) {          // tail (N % 4)
    for (int i = NV << 2; i < N; ++i)
      atomicAdd(&h[(__float_as_uint(x[i]) & 0x7fffffffu) >> HB], 1);
  }
  __syncthreads();
  for (int i = threadIdx.x; i < HIST1_SIZE; i += 256) {
    int c = h[i];
    if (c) atomicAdd(&hist1[i], c);
  }
}

// ---------------- select median buckets + in-bucket ranks + conservative thrLo ----------------
__global__ void k_select(const int* __restrict__ hist1, long long k1, long long k2,
                         int* __restrict__ p) {
  __shared__ int part[256];
  __shared__ long long excl[256];
  __shared__ int b1s, b2s, r1s, r2s;
  int tid = threadIdx.x;
  const int chunk = HIST1_SIZE / 256;  // 32
  int base = tid * chunk;
  int s = 0;
  for (int w = 0; w < chunk; ++w) s += hist1[base + w];
  part[tid] = s;
  __syncthreads();
  if (tid == 0) {
    long long acc = 0;
    for (int i = 0; i < 256; ++i) { excl[i] = acc; acc += part[i]; }
  }
  __syncthreads();
  long long pre = excl[tid];
  if (pre <= k1 && k1 < pre + part[tid]) {
    long long acc = pre;
    for (int w = 0; w < chunk; ++w) {
      int c = hist1[base + w];
      if (k1 < acc + c) { b1s = base + w; r1s = (int)(k1 - acc); break; }
      acc += c;
    }
  }
  if (pre <= k2 && k2 < pre + part[tid]) {
    long long acc = pre;
    for (int w = 0; w < chunk; ++w) {
      int c = hist1[base + w];
      if (k2 < acc + c) { b2s = base + w; r2s = (int)(k2 - acc); break; }
      acc += c;
    }
  }
  __syncthreads();
  if (tid == 0) {
    p[P_B1] = b1s; p[P_B2] = b2s;
    p[P_R1] = r1s; p[P_R2] = r2s;
    // guaranteed lower bound on threshold from bucket lower edges
    float lo1 = __uint_as_float((uint32_t)b1s << HB);
    float lo2 = __uint_as_float((uint32_t)b2s << HB);
    float mLo = 0.5f * (lo1 + lo2);
    p[P_THRLO] = __float_as_int((5.0f * mLo / 0.6745f) * 0.999f);
  }
}

// ---------------- pass 2: compact in-bucket patterns + candidates, 8x batching ----------------
__device__ inline void p2_elem(float f, int idx, int b1, int b2, float thrLo,
                               int* lbuf, int* lcnt, int* list, int* p, int* cand) {
  uint32_t u = __float_as_uint(f) & 0x7fffffffu;
  int top = (int)(u >> HB);
  if (top == b1 || top == b2) {
    int id = atomicAdd(lcnt, 1);
    if (id < LBUF_CAP) lbuf[id] = (int)u;
    else { int g = atomicAdd(&p[P_LISTN], 1); if (g < LIST_CAP) list[g] = (int)u; }
  }
  if (__uint_as_float(u) > thrLo) {
    int id = atomicAdd(&p[P_CANDN], 1);
    if (id < CAND_CAP) cand[id] = idx;
  }
}

__global__ __launch_bounds__(256) void k_pass2(const float* __restrict__ x, int N,
                                               int* __restrict__ p,
                                               int* __restrict__ list,
                                               int* __restrict__ cand) {
  __shared__ int lbuf[LBUF_CAP];
  __shared__ int lcnt;
  __shared__ int lbase;
  if (threadIdx.x == 0) lcnt = 0;
  __syncthreads();
  int b1 = p[P_B1], b2 = p[P_B2];
  float thrLo = __int_as_float(p[P_THRLO]);
  int NV = N >> 2;
  int str = gridDim.x * 256;
  const float4* vec = reinterpret_cast<const float4*>(x);
  int j = blockIdx.x * 256 + threadIdx.x;
  for (; j + 7 * str < NV; j += 8 * str) {
    float4 v[8];
#pragma unroll
    for (int k = 0; k < 8; ++k) v[k] = vec[j + k * str];
#pragma unroll
    for (int k = 0; k < 8; ++k) {
      int base = (j + k * str) << 2;
      p2_elem(v[k].x, base + 0, b1, b2, thrLo, lbuf, &lcnt, list, p, cand);
      p2_elem(v[k].y, base + 1, b1, b2, thrLo, lbuf, &lcnt, list, p, cand);
      p2_elem(v[k].z, base + 2, b1, b2, thrLo, lbuf, &lcnt, list, p, cand);
      p2_elem(v[k].w, base + 3, b1, b2, thrLo, lbuf, &lcnt, list, p, cand);
    }
  }
  for (; j < NV; j += str) {
    float4 a = vec[j];
    int base = j << 2;
    p2_elem(a.x, base + 0, b1, b2, thrLo, lbuf, &lcnt, list, p, cand);
    p2_elem(a.y, base + 1, b1, b2, thrLo, lbuf, &lcnt, list, p, cand);
    p2_elem(a.z, base + 2, b1, b2, thrLo, lbuf, &lcnt, list, p, cand);
    p2_elem(a.w, base + 3, b1, b2, thrLo, lbuf, &lcnt, list, p, cand);
  }
  if (blockIdx.x == 0 && threadIdx.x == 0) {      // tail (N % 4)
    for (int i = NV << 2; i < N; ++i)
      p2_elem(x[i], i, b1, b2, thrLo, lbuf, &lcnt, list, p, cand);
  }
  __syncthreads();
  int n = lcnt < LBUF_CAP ? lcnt : LBUF_CAP;
  if (threadIdx.x == 0) lbase = atomicAdd(&p[P_LISTN], n);
  __syncthreads();
  int base = lbase;
  for (int i = threadIdx.x; i < n; i += 256)
    if (base + i < LIST_CAP) list[base + i] = lbuf[i];
}

// ---------------- stage A: 256-bin hist of bits[17:10] per target; last block selects ----------------
__global__ __launch_bounds__(256) void k_stageA(const int* __restrict__ list,
                                                int* __restrict__ p,
                                                int* __restrict__ histA) {
  __shared__ int h[512];
  __shared__ int lastS;
  __shared__ int sh[256];
  __shared__ int excl[256];
  for (int i = threadIdx.x; i < 512; i += 256) h[i] = 0;
  __syncthreads();
  int n = p[P_LISTN]; if (n > LIST_CAP) n = LIST_CAP;
  int b1 = p[P_B1], b2 = p[P_B2];
  int str = gridDim.x * 256;
  for (int i = blockIdx.x * 256 + threadIdx.x; i < n; i += str) {
    int v = list[i];
    int top = v >> HB;
    int bin = (v >> 10) & 255;
    if (top == b1) atomicAdd(&h[bin], 1);
    if (top == b2) atomicAdd(&h[256 + bin], 1);
  }
  __syncthreads();
  for (int i = threadIdx.x; i < 512; i += 256) {
    int c = h[i];
    if (c) atomicAdd(&histA[i], c);
  }
  __threadfence();
  if (threadIdx.x == 0) lastS = (atomicAdd(&p[P_DONEA], 1) == (int)gridDim.x - 1);
  __syncthreads();
  if (!lastS) return;
  __threadfence();                          // acquire: see all blocks' histA adds
  int tid = threadIdx.x;
  for (int tgt = 0; tgt < 2; ++tgt) {
    int rank = p[P_R1 + tgt];
    int c = histA[tgt * 256 + tid];
    sh[tid] = c;
    __syncthreads();
    if (tid == 0) { int a = 0; for (int i = 0; i < 256; ++i) { excl[i] = a; a += sh[i]; } }
    __syncthreads();
    int pre = excl[tid];
    if (pre <= rank && rank < pre + c) {
      p[P_BINA0 + tgt] = tid;
      p[P_RA0 + tgt] = rank - pre;
    }
    __syncthreads();
  }
}

// ---------------- stage B: 1024-bin hist of bits[9:0]; last block -> exact threshold ----------------
__global__ __launch_bounds__(256) void k_stageB(const int* __restrict__ list,
                                                int* __restrict__ p,
                                                int* __restrict__ histB,
                                                float* __restrict__ outThr) {
  __shared__ int h[2048];
  __shared__ int lastS;
  __shared__ int sh[256];
  __shared__ int excl[256];
  __shared__ float vres[2];
  for (int i = threadIdx.x; i < 2048; i += 256) h[i] = 0;
  __syncthreads();
  int n = p[P_LISTN]; if (n > LIST_CAP) n = LIST_CAP;
  int b1 = p[P_B1], b2 = p[P_B2];
  int bA0 = p[P_BINA0], bA1 = p[P_BINA1];
  int str = gridDim.x * 256;
  for (int i = blockIdx.x * 256 + threadIdx.x; i < n; i += str) {
    int v = list[i];
    int top = v >> HB;
    int bin = (v >> 10) & 255;
    int lo = v & 1023;
    if (top == b1 && bin == bA0) atomicAdd(&h[lo], 1);
    if (top == b2 && bin == bA1) atomicAdd(&h[1024 + lo], 1);
  }
  __syncthreads();
  for (int i = threadIdx.x; i < 2048; i += 256) {
    int c = h[i];
    if (c) atomicAdd(&histB[i], c);
  }
  __threadfence();
  if (threadIdx.x == 0) lastS = (atomicAdd(&p[P_DONEB], 1) == (int)gridDim.x - 1);
  __syncthreads();
  if (!lastS) return;
  __threadfence();
  int tid = threadIdx.x;
  if (tid < 2) vres[tid] = 0.0f;
  for (int tgt = 0; tgt < 2; ++tgt) {
    __syncthreads();
    int rank = p[P_RA0 + tgt];
    const int* hh = histB + tgt * 1024;
    int c0 = hh[tid * 4], c1 = hh[tid * 4 + 1], c2 = hh[tid * 4 + 2], c3 = hh[tid * 4 + 3];
    sh[tid] = c0 + c1 + c2 + c3;
    __syncthreads();
    if (tid == 0) { int a = 0; for (int i = 0; i < 256; ++i) { excl[i] = a; a += sh[i]; } }
    __syncthreads();
    int pre = excl[tid];
    if (pre <= rank && rank < pre + sh[tid]) {
      int a = pre;
      int cc[4] = {c0, c1, c2, c3};
      for (int w = 0; w < 4; ++w) {
        if (rank < a + cc[w]) {
          int bkt = (tgt == 0) ? b1 : b2;
          uint32_t bits = ((uint32_t)bkt << HB) | ((uint32_t)p[P_BINA0 + tgt] << 10) |
                          (uint32_t)(tid * 4 + w);
          vres[tgt] = __uint_as_float(bits);
          break;
        }
        a += cc[w];
      }
    }
  }
  __syncthreads();
  if (tid == 0) {
    float med = 0.5f * (vres[0] + vres[1]);     // np.median: mean of two mid order stats
    float thr = (5.0f * med) / 0.6745f;         // reference float32 expression order
    p[P_THR] = __float_as_int(thr);
    *outThr = thr;                               // out[2*OUT_K]
  }
}

// ---------------- pad output with -1 (peaks + thr slot written later) ----------------
__global__ __launch_bounds__(256) void k_fillpad(float* __restrict__ out, int n2) {
  int j = blockIdx.x * 256 + threadIdx.x;
  if (j < n2) out[j] = -1.0f;
}

// ---------------- finalize: pairs from candidates, windowed argmax, write peaks ----------------
__device__ static void isort(int* a, int n) {
  for (int i = 1; i < n; ++i) {
    int v = a[i]; int j = i - 1;
    while (j >= 0 && a[j] > v) { a[j + 1] = a[j]; --j; }
    a[j + 1] = v;
  }
}

__device__ inline void eval_pair(const float* __restrict__ x, int p, float thr,
                                 int* pe, int* px, int* ne, int* nx, int* cnt) {
  float a = x[p], b = x[p + 1];
  bool m0 = a > thr, m1 = b > thr;
  if (m0 != m1) {
    int id = atomicAdd(&cnt[m1 ? 0 : 1], 1);
    if (id < PAIR_CAP) (m1 ? pe : px)[id] = p;
  }
  bool q0 = (-a) > thr, q1 = (-b) > thr;       // exact ref form: v=-x, v>thr
  if (q0 != q1) {
    int id = atomicAdd(&cnt[q1 ? 2 : 3], 1);
    if (id < PAIR_CAP) (q1 ? ne : nx)[id] = p;
  }
}

__device__ inline int wave_argmax36(const float* __restrict__ x, int N, int sign,
                                    int e, int lane) {
  float val = -INFINITY;
  int wi = lane;
  if (lane < MAX_SPIKE) {
    int idx = e + lane; if (idx > N - 1) idx = N - 1;   // ref: clip(entry+w, 0, N-1)
    float v = x[idx];
    val = (sign < 0) ? -v : v;
  }
  for (int off = 32; off; off >>= 1) {                  // tie -> smaller w (first max)
    float ov = __shfl_xor(val, off);
    int owi = __shfl_xor(wi, off);
    if (ov > val || (ov == val && owi < wi)) { val = ov; wi = owi; }
  }
  return e + wi;
}

__device__ inline int proc_pol(const float* __restrict__ x, int N, int sign,
                               const int* eL, int nE, const int* xL, int nX,
                               int* pk, int tid) {
  int n = nE < nX ? nE : nX;
  int tot = 0;
  for (int t = 0; t < n; ++t) {
    int dur = xL[t] - eL[t];
    if (dur <= MAX_SPIKE) {                    // negative dur kept (ref semantics)
      int pp = wave_argmax36(x, N, sign, eL[t], tid);
      if (tot < PEAK_CAP && tid == 0) pk[tot] = pp;
      ++tot;
    }
  }
  if (tot > PEAK_CAP) tot = PEAK_CAP;
  if (tid == 0) isort(pk, tot);                // ref sorts peaks
  return tot;
}

__global__ void k_finalize(const float* __restrict__ x, int N,
                           int* __restrict__ p, int* __restrict__ cand,
                           float* __restrict__ out, int OUT_K) {
  __shared__ int pe[PAIR_CAP], px[PAIR_CAP], ne[PAIR_CAP], nx[PAIR_CAP];
  __shared__ int cnt[4];
  __shared__ int pkP[PEAK_CAP], pkN[PEAK_CAP];
  __shared__ int nPk[2];
  int tid = threadIdx.x;                        // blockDim = 64 (one wave)
  float thr = __int_as_float(p[P_THR]);
  int nC = p[P_CANDN]; if (nC > CAND_CAP) nC = CAND_CAP;
  if (tid < 4) cnt[tid] = 0;
  __syncthreads();
  if (tid == 0) isort(cand, nC);                // sort candidate indices
  __syncthreads();
  // pair (p,p+1) processed exactly once: from candidate p (right pair),
  // or from candidate p+1 iff p not a candidate.
  for (int k = tid; k < nC; k += 64) {
    int c = cand[k];
    bool prevAdj = (k > 0) && (cand[k - 1] == c - 1);
    if (c > 0 && !prevAdj) eval_pair(x, c - 1, thr, pe, px, ne, nx, cnt);
    if (c <= N - 2) eval_pair(x, c, thr, pe, px, ne, nx, cnt);
  }
  __syncthreads();
  int nPE = min(cnt[0], PAIR_CAP), nPX = min(cnt[1], PAIR_CAP);
  int nNE = min(cnt[2], PAIR_CAP), nNX = min(cnt[3], PAIR_CAP);
  if (tid == 0) { isort(pe, nPE); isort(px, nPX); }
  else if (tid == 1) { isort(ne, nNE); isort(nx, nNX); }
  __syncthreads();
  int t0 = proc_pol(x, N, +1, pe, nPE, px, nPX, pkP, tid);
  int t1 = proc_pol(x, N, -1, ne, nNE, nx, nNX, pkN, tid);
  if (tid == 0) { nPk[0] = t0; nPk[1] = t1; }
  __syncthreads();
  for (int j = tid; j < nPk[0]; j += 64) out[j] = (float)pkP[j];
  for (int j = tid; j < nPk[1]; j += 64) out[OUT_K + j] = (float)pkN[j];
}

extern "C" void kernel_launch(void* const* d_in, const int* in_sizes, int n_in,
                              void* d_out, int out_size, void* d_ws, size_t ws_size,
                              hipStream_t stream) {
  const float* x = (const float*)d_in[0];
  int N = in_sizes[0];
  float* out = (float*)d_out;
  char* ws = (char*)d_ws;

  int* hist1  = (int*)(ws + WS_HIST1);
  int* histA  = (int*)(ws + WS_HISTA);
  int* histB  = (int*)(ws + WS_HISTB);
  int* params = (int*)(ws + WS_PARAMS);
  int* cand   = (int*)(ws + WS_CAND);
  int* list   = (int*)(ws + WS_LIST);

  hipMemsetAsync(d_ws, 0, WS_ZERO_BYTES, stream);

  long long k1 = (long long)(N / 2) - 1;
  long long k2 = (long long)(N / 2);
  int OUT_K = (out_size - 1) / 2;  // 65536

  k_fillpad<<<(2 * OUT_K + 255) / 256, 256, 0, stream>>>(out, 2 * OUT_K);
  k_hist1<<<2048, 256, 0, stream>>>(x, N, hist1);
  k_select<<<1, 256, 0, stream>>>(hist1, k1, k2, params);
  k_pass2<<<2048, 256, 0, stream>>>(x, N, params, list, cand);
  k_stageA<<<STAGE_BLOCKS, 256, 0, stream>>>(list, params, histA);
  k_stageB<<<STAGE_BLOCKS, 256, 0, stream>>>(list, params, histB, out + 2 * OUT_K);
  k_finalize<<<1, 64, 0, stream>>>(x, N, params, cand, out, OUT_K);
}